// Round 1
// 378.248 us; speedup vs baseline: 1.0859x; 1.0859x over previous
//
#include <hip/hip_runtime.h>
#include <math.h>

#define BB 16
#define CC 64
#define HH 224
#define WW 224
#define HWSZ (HH * WW)          // 50176
#define HW4 (HWSZ / 4)          // 12544
#define R 7                     // gate rows per tile (224/7 = 32 tiles)
#define TILES (HH / R)          // 32
#define FR (R + 6)              // 13 feat rows incl ±3 halo
#define FW 240                  // padded LDS feat row width: 3 left pad + 224 + right pad
#define W4 (WW / 4)             // 56
#define T 512                   // threads per block (8 waves)
#define NBLK (BB * TILES)       // 512 blocks = 2 blocks/CU

typedef float f32x4 __attribute__((ext_vector_type(4)));

__global__ __launch_bounds__(T, 4) void fused_kernel(const float* __restrict__ x,
                                                     const float* __restrict__ cw,
                                                     const float* __restrict__ cb,
                                                     float* __restrict__ out) {
    __shared__ float fa[FR * FW];               // avg plane (zero-padded borders)
    __shared__ float fm[FR * FW];               // max plane
    __shared__ alignas(16) float gate[R * WW];  // sigmoid(conv) result
    __shared__ float wt[98];                    // conv weights [2][7][7]

    // XCD-chunked swizzle: 512 blocks = 8 XCDs x 64 chunks (bijective since 512%8==0).
    // Adjacent tiles of one batch land on the same XCD -> halo rows hit XCD-local L2.
    const int blk0 = blockIdx.x;
    const int blk  = (blk0 & 7) * (NBLK / 8) + (blk0 >> 3);
    const int b    = blk >> 5;                  // TILES == 32
    const int tb   = blk & 31;
    const int h0   = tb * R;                    // first gate row of this tile
    const int t    = threadIdx.x;

    // ---- zero-fill feat planes (gives conv its zero padding) + stage weights
    for (int i = t; i < FR * FW; i += T) { fa[i] = 0.f; fm[i] = 0.f; }
    if (t < 98) wt[t] = cw[t];
    __syncthreads();

    // ---- phase 1: channel mean+max over 64 ch -> feat LDS (rows h0-3 .. h0+R+2)
    const f32x4* xb = reinterpret_cast<const f32x4*>(x) + (size_t)b * (CC * HW4);
    for (int p = t; p < FR * W4; p += T) {      // 728 float4 pixels
        int pr = p / W4;
        int pc = p - pr * W4;
        int gh = h0 - 3 + pr;                   // global row
        if ((unsigned)gh >= (unsigned)HH) continue;   // stays zero (padding)
        const f32x4* xp = xb + gh * W4 + pc;
        f32x4 s = {0.f, 0.f, 0.f, 0.f};
        f32x4 m = {-INFINITY, -INFINITY, -INFINITY, -INFINITY};
#pragma unroll 8
        for (int c = 0; c < CC; ++c) {
            f32x4 u = xp[(size_t)c * HW4];
            s += u;
            m[0] = fmaxf(m[0], u[0]); m[1] = fmaxf(m[1], u[1]);
            m[2] = fmaxf(m[2], u[2]); m[3] = fmaxf(m[3], u[3]);
        }
        const float inv = 1.0f / 64.0f;
        int o = pr * FW + 3 + pc * 4;           // +3 = left zero pad
        fa[o + 0] = s[0] * inv; fa[o + 1] = s[1] * inv;
        fa[o + 2] = s[2] * inv; fa[o + 3] = s[3] * inv;
        fm[o + 0] = m[0]; fm[o + 1] = m[1]; fm[o + 2] = m[2]; fm[o + 3] = m[3];
    }
    __syncthreads();

    // ---- phase 2: 7x7 conv (2->1) + bias + sigmoid -> gate LDS
    const float bias = cb[0];
    for (int p = t; p < R * WW; p += T) {       // 1568 gate pixels
        int r = p / WW;
        int w = p - r * WW;
        float acc = bias;
#pragma unroll
        for (int kh = 0; kh < 7; ++kh) {
            int ro = (r + kh) * FW + w;         // LDS col w+kw == global col w+kw-3 (+3 pad)
#pragma unroll
            for (int kw = 0; kw < 7; ++kw) {
                acc = fmaf(fa[ro + kw], wt[kh * 7 + kw], acc);
                acc = fmaf(fm[ro + kw], wt[49 + kh * 7 + kw], acc);
            }
        }
        gate[p] = 1.0f / (1.0f + expf(-acc));
    }
    __syncthreads();

    // ---- phase 3: out = x * gate for all 64 channels of this tile
    f32x4* ob = reinterpret_cast<f32x4*>(out) + (size_t)b * (CC * HW4);
    const f32x4* g4 = reinterpret_cast<const f32x4*>(gate);
    const int NP = R * W4;                      // 392 float4 per channel plane
    for (int i = t; i < CC * NP; i += T) {      // 25088 = 49 * 512, perfectly balanced
        int c  = i / NP;
        int p  = i - c * NP;
        int pr = p / W4;
        int pc = p - pr * W4;
        size_t off = (size_t)c * HW4 + (size_t)(h0 + pr) * W4 + pc;
        f32x4 v = xb[off];
        f32x4 g = g4[p];
        v *= g;
        // out is write-once / never re-read: non-temporal store keeps the LLC
        // free for x (halo + phase-3 re-reads are LLC hits by design).
        __builtin_nontemporal_store(v, ob + off);
    }
}

extern "C" void kernel_launch(void* const* d_in, const int* in_sizes, int n_in,
                              void* d_out, int out_size, void* d_ws, size_t ws_size,
                              hipStream_t stream) {
    const float* x  = (const float*)d_in[0];   // [16,64,224,224]
    const float* cw = (const float*)d_in[1];   // [1,2,7,7]
    const float* cb = (const float*)d_in[2];   // [1]
    float* out = (float*)d_out;

    fused_kernel<<<NBLK, T, 0, stream>>>(x, cw, cb, out);
}